// Round 11
// baseline (124.801 us; speedup 1.0000x reference)
//
#include <hip/hip_runtime.h>
#include <math.h>

#define HH 512
#define WW 512
#define QQ 3

// LDS strip geometry: 16 rows x 256 px, row stride 268 floats (+12 pad).
// SROW=268 -> dword stride 268, bank-quad stride 67 == 3 (mod 8): a wave64
// ds_read_b128 at [r*SROW + nwl*16 + 4*c4] maps its 64 lanes' quad index
// q = (3r + 4*nwl + c4) % 8 uniformly (8 lanes/quad) = throughput-minimum,
// i.e. conflict-free. r9/r10's SROW=260 (quad stride 1 mod 8) put 4 lanes
// per quad -> the measured 4.69M SQ_LDS_BANK_CONFLICT cycles.
// Column b32 access [nwl*16 + r + j*SROW]: lanes cover 64 consecutive dwords
// -> 2 lanes/bank (free, m136). Stage b128 [colv*4 + row*SROW]: uniform.
#define SROW 268
// ytab per-patch stride: 6 vectors x 16 + 8 pad. Writes land 2 lanes/bank;
// reads are 16-lane same-address broadcast (free).
#define YROW 104

// Compiler-only memory fence: orders LDS ops (IR + sched chain edges) without
// pinning all code motion (sched_barrier(0) caused pressure spills, r3/r4).
// HW guarantee: one wave's LDS ops complete in issue order; the row<->column
// data exchange is within a 16-thread quarter-wave group (proven r5/r9/r10).
__device__ __forceinline__ void wfence() { asm volatile("" ::: "memory"); }

// Butterfly with compile-time twiddle index T (0..7), radix-2 DIT, n=16.
template <int SGN, int T>
__device__ __forceinline__ void bfly(float& ar, float& ai, float& br, float& bi) {
  float tr, ti;
  if constexpr (T == 0) {
    tr = br;
    ti = bi;
  } else if constexpr (T == 4) {
    if constexpr (SGN > 0) { tr = bi;  ti = -br; }
    else                   { tr = -bi; ti = br;  }
  } else if constexpr (T == 2) {
    constexpr float c = 0.70710678118654752440f;
    if constexpr (SGN > 0) { tr = c * (br + bi); ti = c * (bi - br); }
    else                   { tr = c * (br - bi); ti = c * (bi + br); }
  } else if constexpr (T == 6) {
    constexpr float c = 0.70710678118654752440f;
    if constexpr (SGN > 0) { tr = c * (bi - br);  ti = -c * (br + bi); }
    else                   { tr = -c * (br + bi); ti = c * (br - bi);  }
  } else {
    constexpr float c1 = 0.92387953251128675613f;   // cos(pi/8)
    constexpr float s1 = 0.38268343236508977173f;   // sin(pi/8)
    constexpr float wr = (T == 1) ? c1 : (T == 3) ? s1 : (T == 5) ? -s1 : -c1;
    constexpr float wi0 = (T == 1) ? -s1 : (T == 3) ? -c1 : (T == 5) ? -c1 : -s1;
    constexpr float wi = (SGN > 0) ? wi0 : -wi0;
    tr = br * wr - bi * wi;
    ti = br * wi + bi * wr;
  }
  br = ar - tr;
  bi = ai - ti;
  ar = ar + tr;
  ai = ai + ti;
}

template <int SGN>
__device__ __forceinline__ void fft16(float re[16], float im[16]) {
#define SW_(a, b)                              \
  { float t = re[a]; re[a] = re[b]; re[b] = t; \
    t = im[a]; im[a] = im[b]; im[b] = t; }
  SW_(1, 8) SW_(2, 4) SW_(3, 12) SW_(5, 10) SW_(7, 14) SW_(11, 13)
#undef SW_
#define BF_(a, b, T) bfly<SGN, T>(re[a], im[a], re[b], im[b]);
  BF_(0, 1, 0) BF_(2, 3, 0) BF_(4, 5, 0) BF_(6, 7, 0)
  BF_(8, 9, 0) BF_(10, 11, 0) BF_(12, 13, 0) BF_(14, 15, 0)
  BF_(0, 2, 0) BF_(1, 3, 4) BF_(4, 6, 0) BF_(5, 7, 4)
  BF_(8, 10, 0) BF_(9, 11, 4) BF_(12, 14, 0) BF_(13, 15, 4)
  BF_(0, 4, 0) BF_(1, 5, 2) BF_(2, 6, 4) BF_(3, 7, 6)
  BF_(8, 12, 0) BF_(9, 13, 2) BF_(10, 14, 4) BF_(11, 15, 6)
  BF_(0, 8, 0) BF_(1, 9, 1) BF_(2, 10, 2) BF_(3, 11, 3)
  BF_(4, 12, 4) BF_(5, 13, 5) BF_(6, 14, 6) BF_(7, 15, 7)
#undef BF_
}

// COALESCED STRIP (r9: dur 64->46us) + COMPLEX PACKING (r10: bench 133->124,
// exact because S is bit-exactly 2D-even) + CONFLICT-FREE STRIDE (r11).
// Block = (image-pair, patch-row, half-strip): stage image A's 16x256 strip
// into xs (Re) and image B's into zim (Im); one complex pipeline; Re->A,
// Im->B at the store. The pair shares the patch, so rank-6 separable S and
// ytab amortize 2x.
__global__ __launch_bounds__(256) void psm_kernel(
    const float* __restrict__ x, const float* __restrict__ logits,
    const float* __restrict__ mu, const float* __restrict__ sigma,
    const float* __restrict__ bias, float* __restrict__ out) {
  __shared__ float xs[16 * SROW];    // image-A strip = Re; later yA strip
  __shared__ float zim[16 * SROW];   // image-B strip = Im; later yB strip
  __shared__ float ytab[16 * YROW];  // 16 patches x 6 y-vectors[16]

  const int tid = threadIdx.x;
  const int bid = blockIdx.x;
  const int half = bid & 1;        // which 256px half of the image row-strip
  const int nh = (bid >> 1) & 31;  // patch-row
  const int pr = bid >> 6;         // image pair (0..31)

  const size_t xbaseA = (size_t)(2 * pr) * (HH * WW) +
                        (size_t)(nh * 16) * WW + (size_t)(half * 256);
  const size_t xbaseB = xbaseA + (size_t)(HH * WW);

  const int w = tid >> 6;     // wave id (0..3)
  const int colv = tid & 63;  // float4 column within strip row

  // ---- stage-in: 8 coalesced float4 loads (A rows then B rows), all issued
  //      before any use so the 8 loads are concurrently in flight ----
  float4 a0, a1, a2, a3, b0, b1, b2, b3;
  {
    const float* srcA = x + xbaseA + (size_t)(colv * 4);
    const float* srcB = x + xbaseB + (size_t)(colv * 4);
    a0 = *(const float4*)(srcA + (size_t)((0 * 4 + w) * WW));
    a1 = *(const float4*)(srcA + (size_t)((1 * 4 + w) * WW));
    a2 = *(const float4*)(srcA + (size_t)((2 * 4 + w) * WW));
    a3 = *(const float4*)(srcA + (size_t)((3 * 4 + w) * WW));
    b0 = *(const float4*)(srcB + (size_t)((0 * 4 + w) * WW));
    b1 = *(const float4*)(srcB + (size_t)((1 * 4 + w) * WW));
    b2 = *(const float4*)(srcB + (size_t)((2 * 4 + w) * WW));
    b3 = *(const float4*)(srcB + (size_t)((3 * 4 + w) * WW));
  }

  const int nwl = tid >> 4;  // patch within strip (16-thread quarter-wave)
  const int r = tid & 15;    // row / j / k index depending on phase
  const int pg = nh * 32 + half * 16 + nwl;  // global patch id

  // ---- Phase A: y-factor tables; overlaps the in-flight stage loads ----
  {
    const float fyr = (float)(r < 8 ? r : r - 16) * (1.0f / 16.0f);
#pragma unroll
    for (int m = 0; m < 6; ++m) {
      const int q = m >> 1;
      const float muy = mu[(pg * QQ + q) * 2 + 0];
      const float isy = 1.0f / sigma[(pg * QQ + q) * 2 + 0];
      const float d = ((m & 1) ? (fyr + muy) : (fyr - muy)) * isy;
      ytab[nwl * YROW + m * 16 + r] = __expf(-0.5f * d * d);
    }
  }

  // ---- park staged rows in LDS ----
  {
    float* dstA = &xs[colv * 4];
    float* dstB = &zim[colv * 4];
    *(float4*)(dstA + (0 * 4 + w) * SROW) = a0;
    *(float4*)(dstA + (1 * 4 + w) * SROW) = a1;
    *(float4*)(dstA + (2 * 4 + w) * SROW) = a2;
    *(float4*)(dstA + (3 * 4 + w) * SROW) = a3;
    *(float4*)(dstB + (0 * 4 + w) * SROW) = b0;
    *(float4*)(dstB + (1 * 4 + w) * SROW) = b1;
    *(float4*)(dstB + (2 * 4 + w) * SROW) = b2;
    *(float4*)(dstB + (3 * 4 + w) * SROW) = b3;
  }
  __syncthreads();  // barrier 1: both strips visible to all waves

  // ---- forward row FFT: thread (nwl, r) owns row r of patch nwl;
  //      re = image A row, im = image B row (complex packing) ----
  float re[16], im[16];
  {
    const float* rbr = &xs[r * SROW + nwl * 16];
    const float* rbi = &zim[r * SROW + nwl * 16];
#pragma unroll
    for (int c4 = 0; c4 < 4; ++c4) {
      const float4 t = *(const float4*)(rbr + c4 * 4);
      const float4 u = *(const float4*)(rbi + c4 * 4);
      re[c4 * 4 + 0] = t.x; re[c4 * 4 + 1] = t.y;
      re[c4 * 4 + 2] = t.z; re[c4 * 4 + 3] = t.w;
      im[c4 * 4 + 0] = u.x; im[c4 * 4 + 1] = u.y;
      im[c4 * 4 + 2] = u.z; im[c4 * 4 + 3] = u.w;
    }
  }
  fft16<1>(re, im);
  {
    float* rbr = &xs[r * SROW + nwl * 16];
    float* rbi = &zim[r * SROW + nwl * 16];
#pragma unroll
    for (int c4 = 0; c4 < 4; ++c4) {
      float4 a, bb;
      a.x = re[c4 * 4 + 0]; a.y = re[c4 * 4 + 1];
      a.z = re[c4 * 4 + 2]; a.w = re[c4 * 4 + 3];
      bb.x = im[c4 * 4 + 0]; bb.y = im[c4 * 4 + 1];
      bb.z = im[c4 * 4 + 2]; bb.w = im[c4 * 4 + 3];
      *(float4*)(rbr + c4 * 4) = a;
      *(float4*)(rbi + c4 * 4) = bb;
    }
  }
  wfence();  // wave-local handoff (column readers = same 16-thread group)

  // ---- column phase: thread (nwl, k=r) owns column k of patch nwl ----
  // s[j] = sum_m ax_m * ay_m[j] (+ jitter/256), wq/256 folded into ax.
  float s[16];
  {
    const float fxk = (float)(r < 8 ? r : r - 16) * (1.0f / 16.0f);
    const float l0 = logits[pg * QQ + 0];
    const float l1 = logits[pg * QQ + 1];
    const float l2 = logits[pg * QQ + 2];
    const float lm = fmaxf(l0, fmaxf(l1, l2));
    const float e0 = __expf(l0 - lm);
    const float e1 = __expf(l1 - lm);
    const float e2 = __expf(l2 - lm);
    const float inv = (1.0f / 256.0f) / (e0 + e1 + e2);
    float ax[6];
#pragma unroll
    for (int m = 0; m < 6; ++m) {
      const int q = m >> 1;
      const float mux = mu[(pg * QQ + q) * 2 + 1];
      const float isx = 1.0f / sigma[(pg * QQ + q) * 2 + 1];
      const float d = ((m & 1) ? (fxk + mux) : (fxk - mux)) * isx;
      const float wqv = ((q == 0) ? e0 : (q == 1) ? e1 : e2) * inv;
      ax[m] = wqv * __expf(-0.5f * d * d);
    }
    const float* yt = &ytab[nwl * YROW];
#pragma unroll
    for (int j4 = 0; j4 < 4; ++j4) {
      const float4 a0v = *(const float4*)(yt + 0 * 16 + j4 * 4);
      const float4 a1v = *(const float4*)(yt + 1 * 16 + j4 * 4);
      const float4 a2v = *(const float4*)(yt + 2 * 16 + j4 * 4);
      const float4 a3v = *(const float4*)(yt + 3 * 16 + j4 * 4);
      const float4 a4v = *(const float4*)(yt + 4 * 16 + j4 * 4);
      const float4 a5v = *(const float4*)(yt + 5 * 16 + j4 * 4);
      s[j4 * 4 + 0] = a0v.x * ax[0] + a1v.x * ax[1] + a2v.x * ax[2] +
                      a3v.x * ax[3] + a4v.x * ax[4] + a5v.x * ax[5] + 3.90625e-9f;
      s[j4 * 4 + 1] = a0v.y * ax[0] + a1v.y * ax[1] + a2v.y * ax[2] +
                      a3v.y * ax[3] + a4v.y * ax[4] + a5v.y * ax[5] + 3.90625e-9f;
      s[j4 * 4 + 2] = a0v.z * ax[0] + a1v.z * ax[1] + a2v.z * ax[2] +
                      a3v.z * ax[3] + a4v.z * ax[4] + a5v.z * ax[5] + 3.90625e-9f;
      s[j4 * 4 + 3] = a0v.w * ax[0] + a1v.w * ax[1] + a2v.w * ax[2] +
                      a3v.w * ax[3] + a4v.w * ax[4] + a5v.w * ax[5] + 3.90625e-9f;
    }
  }
  {
    const float* cbr = &xs[nwl * 16 + r];
    const float* cbi = &zim[nwl * 16 + r];
#pragma unroll
    for (int j = 0; j < 16; ++j) {
      re[j] = cbr[j * SROW];
      im[j] = cbi[j * SROW];
    }
  }
  fft16<1>(re, im);
#pragma unroll
  for (int j = 0; j < 16; ++j) {
    re[j] *= s[j];
    im[j] *= s[j];
  }
  fft16<-1>(re, im);
  {
    float* cbr = &xs[nwl * 16 + r];
    float* cbi = &zim[nwl * 16 + r];
#pragma unroll
    for (int j = 0; j < 16; ++j) {
      cbr[j * SROW] = re[j];
      cbi[j * SROW] = im[j];
    }
  }
  wfence();  // wave-local handoff (row readers = same group)

  // ---- inverse row FFT; Re -> yA, Im -> yB; +bias; back into strips ----
  {
    const float* rbr = &xs[r * SROW + nwl * 16];
    const float* rbi = &zim[r * SROW + nwl * 16];
#pragma unroll
    for (int c4 = 0; c4 < 4; ++c4) {
      const float4 t = *(const float4*)(rbr + c4 * 4);
      const float4 u = *(const float4*)(rbi + c4 * 4);
      re[c4 * 4 + 0] = t.x; re[c4 * 4 + 1] = t.y;
      re[c4 * 4 + 2] = t.z; re[c4 * 4 + 3] = t.w;
      im[c4 * 4 + 0] = u.x; im[c4 * 4 + 1] = u.y;
      im[c4 * 4 + 2] = u.z; im[c4 * 4 + 3] = u.w;
    }
  }
  fft16<-1>(re, im);
  {
    const float* brow = bias + (size_t)pg * 256 + (size_t)(r * 16);
    float* rba = &xs[r * SROW + nwl * 16];
    float* rbb = &zim[r * SROW + nwl * 16];
#pragma unroll
    for (int c4 = 0; c4 < 4; ++c4) {
      const float4 bv = *(const float4*)(brow + c4 * 4);
      float4 oA, oB;
      oA.x = re[c4 * 4 + 0] + bv.x;
      oA.y = re[c4 * 4 + 1] + bv.y;
      oA.z = re[c4 * 4 + 2] + bv.z;
      oA.w = re[c4 * 4 + 3] + bv.w;
      oB.x = im[c4 * 4 + 0] + bv.x;
      oB.y = im[c4 * 4 + 1] + bv.y;
      oB.z = im[c4 * 4 + 2] + bv.z;
      oB.w = im[c4 * 4 + 3] + bv.w;
      *(float4*)(rba + c4 * 4) = oA;
      *(float4*)(rbb + c4 * 4) = oB;
    }
  }
  __syncthreads();  // barrier 2: output strips complete

  // ---- stage-out: 8 coalesced float4 stores ----
  {
    float* dstA = out + xbaseA + (size_t)(colv * 4);
    float* dstB = out + xbaseB + (size_t)(colv * 4);
    const float* srcA = &xs[colv * 4];
    const float* srcB = &zim[colv * 4];
#pragma unroll
    for (int j = 0; j < 4; ++j) {
      const float4 tA = *(const float4*)(srcA + (j * 4 + w) * SROW);
      *(float4*)(dstA + (size_t)((j * 4 + w) * WW)) = tA;
    }
#pragma unroll
    for (int j = 0; j < 4; ++j) {
      const float4 tB = *(const float4*)(srcB + (j * 4 + w) * SROW);
      *(float4*)(dstB + (size_t)((j * 4 + w) * WW)) = tB;
    }
  }
}

extern "C" void kernel_launch(void* const* d_in, const int* in_sizes, int n_in,
                              void* d_out, int out_size, void* d_ws,
                              size_t ws_size, hipStream_t stream) {
  (void)in_sizes;
  (void)n_in;
  (void)out_size;
  (void)d_ws;
  (void)ws_size;
  const float* x = (const float*)d_in[0];
  const float* logits = (const float*)d_in[1];
  const float* mu = (const float*)d_in[2];
  const float* sigma = (const float*)d_in[3];
  const float* bias = (const float*)d_in[4];
  float* out = (float*)d_out;

  // 32 image-pairs x 32 patch-rows x 2 half-strips = 2048 blocks.
  psm_kernel<<<dim3(32 * 32 * 2), dim3(256), 0, stream>>>(x, logits, mu, sigma,
                                                          bias, out);
}